// Round 5
// baseline (307.246 us; speedup 1.0000x reference)
//
#include <hip/hip_runtime.h>
#include <hip/hip_cooperative_groups.h>
#include <cstdint>
#include <cstddef>

namespace cg = cooperative_groups;

typedef int int32x4  __attribute__((ext_vector_type(4)));
typedef int int32x16 __attribute__((ext_vector_type(16)));

#define AS1 __attribute__((address_space(1)))
#define AS3 __attribute__((address_space(3)))

__device__ __forceinline__ void gload_lds16(const void* g, void* l) {
    __builtin_amdgcn_global_load_lds((const AS1 void*)g, (AS3 void*)l, 16, 0, 0);
}

#define MFMA_I8(a, b, c) __builtin_amdgcn_mfma_i32_32x32x32_i8((a), (b), (c), 0, 0, 0)

// ---------------------------------------------------------------------------
// SINGLE cooperative kernel: quant(x,y) + sy reduction + int8 GEMM.
// Why: rounds 0-4 showed total - gemm == 156±3us in EVERY round, insensitive
// to quant rewrites and 2->1 quant fusion; no quant dispatch ever entered
// top-5 (each < 82us) while roofline for the quant path is ~25us. The
// remaining time is either slow quant dispatches or inter-dispatch
// serialization — indistinguishable from outside. Fusing everything into one
// dispatch removes memset + 2 launches + graph edges AND makes whatever
// remains visible in one dispatch's counters.
// Geometry: grid 256 x 512thr, 1 block/CU (128KB LDS), cooperative.
//  Phase 0: block b quantizes x-rows [16b,16b+16) -> A8 + rs (exclusive, no
//    atomics) and y-tiles q in [16b,16b+16) (64x64 dword-pack LDS transpose,
//    proven r1) -> B8T; col-sum partials kept in LDS; zeros sy[16b..16b+16).
//  grid.sync()
//  Phase 1: scatter 1024 LDS partials -> sy via global atomics.
//  grid.sync()
//  Phase 2: r4 gemm body VERBATIM (best: 82us, MfmaUtil 38.7): 256x256
//    tile, 8 waves 2Mx4N, 4-buffer LDS ring, cross-tile register frag
//    double-buffer, counted vmcnt, one barrier/tile.
// LDS union: quant scratch (tbuf 8704B + wsum 64B + ssum 4KB) overlays the
// As region; gemm staging begins only after phase 1 consumed ssum.
// Frags: A[m=lane&31][k=(lane>>5)*16+j]; C/D col=lane&31,
// row=(reg&3)+8*(reg>>2)+4*(lane>>5)  (verified r0-r4, absmax 32).
// Epilogue: C = 7.5e-4 * (P - 32*rs[m] + 66*sy[n] - 8650752)
// ---------------------------------------------------------------------------
__global__ __launch_bounds__(512, 2) void fused_qgemm(const float* __restrict__ x,
                                                      const float* __restrict__ y,
                                                      signed char* __restrict__ A8,
                                                      signed char* __restrict__ B8T,
                                                      int* __restrict__ rs,
                                                      int* __restrict__ sy,
                                                      float* __restrict__ C) {
    __shared__ __align__(16) signed char smem[131072];
    const int tid = threadIdx.x;
    const int b = blockIdx.x;

    // ======================= PHASE 0: quant =======================
    {
        int* tbuf = (int*)smem;                  // 2 x 1088 ints (y-tile bufs)
        int* wsum = (int*)(smem + 8704);         // 8 ints
        int* ssum = (int*)(smem + 8768);         // 1024 ints (16 tiles x 64 cols)
        if (tid < 16) sy[16 * b + tid] = 0;      // zero own sy slice
        ssum[tid] = 0; ssum[tid + 512] = 0;
        __syncthreads();

        const int half = tid >> 8;               // 0/1: which row/tile of the pair
        const int t2 = tid & 255;

        // ---- x: 16 rows, 2 per iteration ----
        for (int it = 0; it < 8; ++it) {
            const int row = 16 * b + 2 * it + half;
            const float4* xr = (const float4*)(x + (size_t)row * 4096);
            char4* ar = (char4*)(A8 + (size_t)row * 4096);
            int s = 0;
#pragma unroll
            for (int i = 0; i < 4; i++) {
                const int idx = i * 256 + t2;
                float4 v = xr[idx];
                int a0 = (int)v.x, a1 = (int)v.y, a2 = (int)v.z, a3 = (int)v.w;
                s += a0 + a1 + a2 + a3;
                char4 c;
                c.x = (signed char)a0; c.y = (signed char)a1;
                c.z = (signed char)a2; c.w = (signed char)a3;
                ar[idx] = c;
            }
#pragma unroll
            for (int off = 32; off > 0; off >>= 1) s += __shfl_down(s, off);
            if ((tid & 63) == 0) wsum[tid >> 6] = s;   // waves 0-3: row A, 4-7: row B
            __syncthreads();
            if (t2 == 0)
                rs[row] = wsum[half * 4 + 0] + wsum[half * 4 + 1] +
                          wsum[half * 4 + 2] + wsum[half * 4 + 3];
            __syncthreads();                           // wsum reused next iter
        }

        // ---- y: 16 tiles (64x64), 2 per iteration, dword-pack transpose ----
        {
            int* tb = tbuf + half * 1088;        // 64*17 ints per tile buffer
            const int n4 = (t2 & 15) * 4;
            const int kb = (t2 >> 4) * 4;
            for (int it = 0; it < 8; ++it) {
                const int jloc = 2 * it + half;
                const int q = 16 * b + jloc;
                const int nt = (q & 63) * 64;
                const int kt = (q >> 6) * 64;
                int bb[4][4];
#pragma unroll
                for (int i = 0; i < 4; i++) {
                    float4 v = *(const float4*)(y + (size_t)(kt + kb + i) * 4096 + nt + n4);
                    bb[i][0] = (int)v.x - 128; bb[i][1] = (int)v.y - 128;
                    bb[i][2] = (int)v.z - 128; bb[i][3] = (int)v.w - 128;
                }
#pragma unroll
                for (int j = 0; j < 4; j++) {
                    const int s = bb[0][j] + bb[1][j] + bb[2][j] + bb[3][j];
                    const int w = (bb[0][j] & 255) | ((bb[1][j] & 255) << 8) |
                                  ((bb[2][j] & 255) << 16) | (bb[3][j] << 24);
                    tb[(n4 + j) * 17 + (kb >> 2)] = w;
                    atomicAdd(&ssum[jloc * 64 + n4 + j], s);
                }
                __syncthreads();
                const int n = t2 >> 2;
                const int kq = (t2 & 3) * 4;
                int32x4 o;
                o.x = tb[n * 17 + kq + 0];
                o.y = tb[n * 17 + kq + 1];
                o.z = tb[n * 17 + kq + 2];
                o.w = tb[n * 17 + kq + 3];
                *(int32x4*)(B8T + (size_t)(nt + n) * 4096 + kt + kq * 4) = o;
                __syncthreads();                 // tb reused next iter
            }
        }

        cg::this_grid().sync();   // A8/B8T/rs complete + all sy slices zeroed

        // ---- PHASE 1: scatter col-sum partials into sy ----
#pragma unroll
        for (int p = tid; p < 1024; p += 512) {
            const int q = 16 * b + (p >> 6);
            const int nt = (q & 63) * 64;
            atomicAdd(&sy[nt + (p & 63)], ssum[p]);
        }
        cg::this_grid().sync();   // sy final before any epilogue
    }

    // ======================= PHASE 2: gemm (r4 body) =======================
    signed char* As = (signed char*)smem;            // 4 x 16384
    signed char* Bs = (signed char*)smem + 65536;    // 4 x 16384
    const int lin = b;
    const int til = (lin & 7) * 32 + (lin >> 3);     // XCD-contiguous tiles
    const int bm = (til >> 4) * 256;
    const int bn = (til & 15) * 256;
    const int lane = tid & 63;
    const int wave = tid >> 6;
    const int wm = (wave >> 2) * 128;   // 2 m-waves x 128
    const int wn = (wave & 3) * 64;     // 4 n-waves x 64
    const int mr = lane & 31;
    const int kh = lane >> 5;

    int32x16 acc[4][2] = {};

    const int srow = tid >> 2;
    const int scol = ((tid & 3) ^ ((tid >> 3) & 3)) * 16;
    const size_t arow = (size_t)(bm + srow) * 4096 + scol;
    const size_t brow = (size_t)(bn + srow) * 4096 + scol;

    int aoff[4][2], boff[2][2];
#pragma unroll
    for (int ks = 0; ks < 2; ks++) {
        const int slot = ((ks * 2 + kh) ^ ((mr >> 1) & 3)) * 16;
#pragma unroll
        for (int i = 0; i < 4; i++) aoff[i][ks] = (wm + i * 32 + mr) * 64 + slot;
#pragma unroll
        for (int j = 0; j < 2; j++) boff[j][ks] = (wn + j * 32 + mr) * 64 + slot;
    }

    auto stage = [&](int buf, int kt) {   // prologue: 4 gloads (2 A + 2 B)
        signed char* a_dst = As + buf * 16384 + tid * 16;
        signed char* b_dst = Bs + buf * 16384 + tid * 16;
#pragma unroll
        for (int p = 0; p < 2; p++)
            gload_lds16(A8 + arow + (size_t)p * 524288 + kt, a_dst + p * 8192);
#pragma unroll
        for (int p = 0; p < 2; p++)
            gload_lds16(B8T + brow + (size_t)p * 524288 + kt, b_dst + p * 8192);
    };

    stage(0, 0);
    stage(1, 64);
    stage(2, 128);
    // 0xF78 = vmcnt(8), 0xF74 = vmcnt(4), 0xF70 = vmcnt(0).
    __builtin_amdgcn_s_waitcnt(0xF78);   // tile 0 landed (tiles 1,2 in flight)
    __builtin_amdgcn_s_barrier();
    __builtin_amdgcn_sched_barrier(0);

    int32x4 xa[4], xb[2];   // ks0 frags of current tile
    int32x4 ya[4], yb[2];   // ks1 frags of current tile
#pragma unroll
    for (int i = 0; i < 4; i++) xa[i] = *(const int32x4*)(As + aoff[i][0]);
#pragma unroll
    for (int j = 0; j < 2; j++) xb[j] = *(const int32x4*)(Bs + boff[j][0]);

#pragma unroll 1
    for (int tt = 0; tt < 64; ++tt) {
        const signed char* Ab  = As + (tt & 3) * 16384;        // tile tt
        const signed char* Bb  = Bs + (tt & 3) * 16384;
        const signed char* Abn = As + ((tt + 1) & 3) * 16384;  // tile tt+1
        const signed char* Bbn = Bs + ((tt + 1) & 3) * 16384;
        signed char* a_dst = As + ((tt + 3) & 3) * 16384 + tid * 16;
        signed char* b_dst = Bs + ((tt + 3) & 3) * 16384 + tid * 16;
        const size_t gk = (size_t)(tt + 3) * 64;
        const bool st = (tt < 61);

        if (tt == 62) __builtin_amdgcn_s_waitcnt(0xF70);  // only tile 63 left
        else          __builtin_amdgcn_s_waitcnt(0xF74);  // tiles <= tt+1 done
        __builtin_amdgcn_s_barrier();
        __builtin_amdgcn_sched_barrier(0);

        // ---- half 0: refill Y <- tile tt ks1; stage A of tt+3; MFMA X ----
#pragma unroll
        for (int i = 0; i < 4; i++) ya[i] = *(const int32x4*)(Ab + aoff[i][1]);
#pragma unroll
        for (int j = 0; j < 2; j++) yb[j] = *(const int32x4*)(Bb + boff[j][1]);
        if (st) {
            gload_lds16(A8 + arow + gk, a_dst);
            gload_lds16(A8 + arow + 524288 + gk, a_dst + 8192);
        }
        __builtin_amdgcn_sched_barrier(0);
        __builtin_amdgcn_s_setprio(1);
        acc[0][0] = MFMA_I8(xa[0], xb[0], acc[0][0]);
        acc[0][1] = MFMA_I8(xa[0], xb[1], acc[0][1]);
        acc[1][0] = MFMA_I8(xa[1], xb[0], acc[1][0]);
        acc[1][1] = MFMA_I8(xa[1], xb[1], acc[1][1]);
        acc[2][0] = MFMA_I8(xa[2], xb[0], acc[2][0]);
        acc[2][1] = MFMA_I8(xa[2], xb[1], acc[2][1]);
        acc[3][0] = MFMA_I8(xa[3], xb[0], acc[3][0]);
        acc[3][1] = MFMA_I8(xa[3], xb[1], acc[3][1]);
        __builtin_amdgcn_s_setprio(0);

        // ---- half 1: refill X <- tile tt+1 ks0; stage B of tt+3; MFMA Y ----
        if (tt < 63) {
#pragma unroll
            for (int i = 0; i < 4; i++) xa[i] = *(const int32x4*)(Abn + aoff[i][0]);
#pragma unroll
            for (int j = 0; j < 2; j++) xb[j] = *(const int32x4*)(Bbn + boff[j][0]);
        }
        if (st) {
            gload_lds16(B8T + brow + gk, b_dst);
            gload_lds16(B8T + brow + 524288 + gk, b_dst + 8192);
        }
        __builtin_amdgcn_sched_barrier(0);
        __builtin_amdgcn_s_setprio(1);
        acc[0][0] = MFMA_I8(ya[0], yb[0], acc[0][0]);
        acc[0][1] = MFMA_I8(ya[0], yb[1], acc[0][1]);
        acc[1][0] = MFMA_I8(ya[1], yb[0], acc[1][0]);
        acc[1][1] = MFMA_I8(ya[1], yb[1], acc[1][1]);
        acc[2][0] = MFMA_I8(ya[2], yb[0], acc[2][0]);
        acc[2][1] = MFMA_I8(ya[2], yb[1], acc[2][1]);
        acc[3][0] = MFMA_I8(ya[3], yb[0], acc[3][0]);
        acc[3][1] = MFMA_I8(ya[3], yb[1], acc[3][1]);
        __builtin_amdgcn_s_setprio(0);
    }

    // Epilogue. C/D: col = lane&31, row = (reg&3) + 8*(reg>>2) + 4*kh
#pragma unroll
    for (int i = 0; i < 4; i++) {
#pragma unroll
        for (int r = 0; r < 16; r++) {
            const int gm = bm + wm + i * 32 + (r & 3) + 8 * (r >> 2) + 4 * kh;
            const int rcorr = -32 * rs[gm] - 8650752;
#pragma unroll
            for (int j = 0; j < 2; j++) {
                const int gn = bn + wn + j * 32 + mr;
                const int v = acc[i][j][r] + rcorr + 66 * sy[gn];
                C[(size_t)gm * 4096 + gn] = 7.5e-4f * (float)v;
            }
        }
    }
}

// ---------------------------------------------------------------------------
extern "C" void kernel_launch(void* const* d_in, const int* in_sizes, int n_in,
                              void* d_out, int out_size, void* d_ws, size_t ws_size,
                              hipStream_t stream) {
    const float* x = (const float*)d_in[0];  // [4096,4096] int8-valued
    const float* y = (const float*)d_in[1];  // [4096,4096] uint8-valued
    float* out = (float*)d_out;

    char* ws = (char*)d_ws;
    signed char* A8  = (signed char*)ws;                         // 16 MiB
    signed char* B8T = (signed char*)(ws + (16u << 20));         // 16 MiB
    int* rs = (int*)(ws + (32u << 20));                          // 16 KiB
    int* sy = (int*)(ws + (32u << 20) + (16u << 10));            // 16 KiB

    void* args[] = {(void*)&x, (void*)&y, (void*)&A8, (void*)&B8T,
                    (void*)&rs, (void*)&sy, (void*)&out};
    hipLaunchCooperativeKernel((const void*)fused_qgemm, dim3(256), dim3(512),
                               args, 0, stream);
}

// Round 6
// 241.708 us; speedup vs baseline: 1.2711x; 1.2711x over previous
//
#include <hip/hip_runtime.h>
#include <cstdint>
#include <cstddef>

typedef int int32x4  __attribute__((ext_vector_type(4)));
typedef int int32x16 __attribute__((ext_vector_type(16)));

#define AS1 __attribute__((address_space(1)))
#define AS3 __attribute__((address_space(3)))

__device__ __forceinline__ void gload_lds16(const void* g, void* l) {
    __builtin_amdgcn_global_load_lds((const AS1 void*)g, (AS3 void*)l, 16, 0, 0);
}

#define MFMA_I8(a, b, c) __builtin_amdgcn_mfma_i32_32x32x32_i8((a), (b), (c), 0, 0, 0)

// ---------------------------------------------------------------------------
// Fused quant kernel. Blocks [0,4096): x-rows (proven path). Blocks
// [4096,5120): y 256n x 64k tiles, REWRITTEN for coalescing: each wave reads
// 1KB contiguous per instruction (r1-r4 version read 256B/row segments).
// Per thread: 4 outers x 4 k-rows x float4(4n) -> pack 4 k-bytes/dword ->
// XOR-swizzled dword LDS transpose -> b128 stores (4 lanes = 64B per row).
// Col sums held in registers across outers; LDS ssum + 1 global atomic/n.
// r5 lesson: quant needs fat-grid TLP, not fusion into the gemm (coop quant
// phase ran 110us vs ~42us as a dispatch).
// ---------------------------------------------------------------------------
__global__ __launch_bounds__(256) void quant_xy(const float* __restrict__ x,
                                                const float* __restrict__ y,
                                                signed char* __restrict__ A8,
                                                signed char* __restrict__ B8T,
                                                int* __restrict__ rs,
                                                int* __restrict__ sy) {
    const int t = threadIdx.x;
    if (blockIdx.x < 4096) {
        // ---- x path: fp32 -> int8 + row sum (unchanged) ----
        const int row = blockIdx.x;
        const float4* xr = (const float4*)(x + (size_t)row * 4096);
        char4* ar = (char4*)(A8 + (size_t)row * 4096);
        int s = 0;
#pragma unroll
        for (int i = 0; i < 4; i++) {
            const int idx = i * 256 + t;
            float4 v = xr[idx];
            int a0 = (int)v.x, a1 = (int)v.y, a2 = (int)v.z, a3 = (int)v.w;
            s += a0 + a1 + a2 + a3;
            char4 c;
            c.x = (signed char)a0; c.y = (signed char)a1;
            c.z = (signed char)a2; c.w = (signed char)a3;
            ar[idx] = c;
        }
#pragma unroll
        for (int off = 32; off > 0; off >>= 1) s += __shfl_down(s, off);
        __shared__ int wsum[4];
        if ((t & 63) == 0) wsum[t >> 6] = s;
        __syncthreads();
        if (t == 0) rs[row] = wsum[0] + wsum[1] + wsum[2] + wsum[3];
    } else {
        // ---- y path: 256n x 64k tile, coalesced ----
        const int q = blockIdx.x - 4096;            // 0..1023
        const int nt = (q & 15) * 256;
        const int kt = (q >> 4) * 64;
        __shared__ int tile_s[256 * 16];            // [n][kd], XOR-swizzled
        __shared__ int ssum[256];
        if (t < 256) ssum[t] = 0;
        __syncthreads();

        const int n4 = (t & 63) * 4;                // 4 n-cols per thread
        const int kg = (t >> 6) * 4;                // k-row group within outer
        const int swzkey = t & 15;                  // == ((n4+j)>>2)&15 for j<4
        int s0 = 0, s1 = 0, s2 = 0, s3 = 0;
#pragma unroll
        for (int o = 0; o < 4; o++) {
            int b[4][4];
#pragma unroll
            for (int i = 0; i < 4; i++) {
                const int k = o * 16 + kg + i;      // wave reads 1KB contiguous
                float4 v = *(const float4*)(y + (size_t)(kt + k) * 4096 + nt + n4);
                b[i][0] = (int)v.x - 128; b[i][1] = (int)v.y - 128;
                b[i][2] = (int)v.z - 128; b[i][3] = (int)v.w - 128;
            }
            const int kd = o * 4 + (t >> 6);        // dword index along k
            const int sw = kd ^ swzkey;
#pragma unroll
            for (int j = 0; j < 4; j++) {
                const int w = (b[0][j] & 255) | ((b[1][j] & 255) << 8) |
                              ((b[2][j] & 255) << 16) | (b[3][j] << 24);
                tile_s[(n4 + j) * 16 + sw] = w;
            }
            s0 += b[0][0] + b[1][0] + b[2][0] + b[3][0];
            s1 += b[0][1] + b[1][1] + b[2][1] + b[3][1];
            s2 += b[0][2] + b[1][2] + b[2][2] + b[3][2];
            s3 += b[0][3] + b[1][3] + b[2][3] + b[3][3];
        }
        atomicAdd(&ssum[n4 + 0], s0);
        atomicAdd(&ssum[n4 + 1], s1);
        atomicAdd(&ssum[n4 + 2], s2);
        atomicAdd(&ssum[n4 + 3], s3);
        __syncthreads();

        // readout: 4 lanes cover 64B of one n-row (coalesced 64B quads)
        const int c = t & 3;                        // 16B chunk within row
#pragma unroll
        for (int p = 0; p < 4; p++) {
            const int n = (t >> 2) + p * 64;
            const int key = (n >> 2) & 15;
            int32x4 o;
            o.x = tile_s[n * 16 + ((c * 4 + 0) ^ key)];
            o.y = tile_s[n * 16 + ((c * 4 + 1) ^ key)];
            o.z = tile_s[n * 16 + ((c * 4 + 2) ^ key)];
            o.w = tile_s[n * 16 + ((c * 4 + 3) ^ key)];
            *(int32x4*)(B8T + (size_t)(nt + n) * 4096 + kt + c * 16) = o;
        }
        if (t < 256) atomicAdd(&sy[nt + t], ssum[t]);
    }
}

// ---------------------------------------------------------------------------
// Kernel 3: int8 GEMM — r4 body VERBATIM (best measured: 82us, MfmaUtil
// 38.7%). Cross-tile REGISTER double-buffering of fragments: frags for
// half-tile h+1 are ds_read WHILE the MFMAs of half h run; MFMAs never wait
// on lgkm; one barrier/tile. 4-buffer LDS ring (128KB), stage tile t+3 at
// tile t, counted vmcnt(4) at top (tiles <= t+1 complete, t+2 in flight).
// Geometry: BM=BN=256, BK=64, 8 waves 2Mx4N, wave tile 128x64 = 4x2 of
// 32x32x32 i8 MFMA. XOR chunk swizzle at global source (LDS dest linear).
// Frags: A[m=lane&31][k=(lane>>5)*16+j]; C/D col=lane&31,
// row=(reg&3)+8*(reg>>2)+4*(lane>>5)  (verified r0-r5, absmax 32).
// Epilogue: C = 7.5e-4 * (P - 32*rs[m] + 66*sy[n] - 8650752)
// ---------------------------------------------------------------------------
__global__ __launch_bounds__(512, 2) void gemm_i8(const signed char* __restrict__ A8,
                                                  const signed char* __restrict__ B8T,
                                                  const int* __restrict__ rs,
                                                  const int* __restrict__ sy,
                                                  float* __restrict__ C) {
    __shared__ __align__(16) signed char As[4 * 16384];  // 256 rows x 64B x 4
    __shared__ __align__(16) signed char Bs[4 * 16384];  // 256 rows x 64B x 4
    const int tid = threadIdx.x;
    const int lin = blockIdx.x;
    const int til = (lin & 7) * 32 + (lin >> 3);   // XCD-contiguous tiles
    const int bm = (til >> 4) * 256;
    const int bn = (til & 15) * 256;
    const int lane = tid & 63;
    const int wave = tid >> 6;
    const int wm = (wave >> 2) * 128;   // 2 m-waves x 128
    const int wn = (wave & 3) * 64;     // 4 n-waves x 64
    const int mr = lane & 31;
    const int kh = lane >> 5;

    int32x16 acc[4][2] = {};

    const int srow = tid >> 2;
    const int scol = ((tid & 3) ^ ((tid >> 3) & 3)) * 16;
    const size_t arow = (size_t)(bm + srow) * 4096 + scol;
    const size_t brow = (size_t)(bn + srow) * 4096 + scol;

    // fragment LDS offsets: row = wtile + i*32 + mr; chunk = ks*2 + kh;
    // phys slot = chunk ^ ((mr>>1)&3)
    int aoff[4][2], boff[2][2];
#pragma unroll
    for (int ks = 0; ks < 2; ks++) {
        const int slot = ((ks * 2 + kh) ^ ((mr >> 1) & 3)) * 16;
#pragma unroll
        for (int i = 0; i < 4; i++) aoff[i][ks] = (wm + i * 32 + mr) * 64 + slot;
#pragma unroll
        for (int j = 0; j < 2; j++) boff[j][ks] = (wn + j * 32 + mr) * 64 + slot;
    }

    auto stage = [&](int buf, int kt) {   // prologue: 4 gloads (2 A + 2 B)
        signed char* a_dst = As + buf * 16384 + tid * 16;
        signed char* b_dst = Bs + buf * 16384 + tid * 16;
#pragma unroll
        for (int p = 0; p < 2; p++)
            gload_lds16(A8 + arow + (size_t)p * 524288 + kt, a_dst + p * 8192);
#pragma unroll
        for (int p = 0; p < 2; p++)
            gload_lds16(B8T + brow + (size_t)p * 524288 + kt, b_dst + p * 8192);
    };

    stage(0, 0);
    stage(1, 64);
    stage(2, 128);
    // 0xF78 = vmcnt(8), 0xF74 = vmcnt(4), 0xF70 = vmcnt(0).
    __builtin_amdgcn_s_waitcnt(0xF78);   // tile 0 landed (tiles 1,2 in flight)
    __builtin_amdgcn_s_barrier();
    __builtin_amdgcn_sched_barrier(0);

    int32x4 xa[4], xb[2];   // ks0 frags of current tile
    int32x4 ya[4], yb[2];   // ks1 frags of current tile
#pragma unroll
    for (int i = 0; i < 4; i++) xa[i] = *(const int32x4*)(As + aoff[i][0]);
#pragma unroll
    for (int j = 0; j < 2; j++) xb[j] = *(const int32x4*)(Bs + boff[j][0]);

#pragma unroll 1
    for (int t = 0; t < 64; ++t) {
        const signed char* Ab  = As + (t & 3) * 16384;        // tile t
        const signed char* Bb  = Bs + (t & 3) * 16384;
        const signed char* Abn = As + ((t + 1) & 3) * 16384;  // tile t+1
        const signed char* Bbn = Bs + ((t + 1) & 3) * 16384;
        signed char* a_dst = As + ((t + 3) & 3) * 16384 + tid * 16;
        signed char* b_dst = Bs + ((t + 3) & 3) * 16384 + tid * 16;
        const size_t gk = (size_t)(t + 3) * 64;
        const bool st = (t < 61);

        if (t == 62) __builtin_amdgcn_s_waitcnt(0xF70);  // only tile 63 left
        else         __builtin_amdgcn_s_waitcnt(0xF74);  // tiles <= t+1 done
        __builtin_amdgcn_s_barrier();
        __builtin_amdgcn_sched_barrier(0);

        // ---- half 0: refill Y <- tile t ks1; stage A of t+3; MFMA X ----
#pragma unroll
        for (int i = 0; i < 4; i++) ya[i] = *(const int32x4*)(Ab + aoff[i][1]);
#pragma unroll
        for (int j = 0; j < 2; j++) yb[j] = *(const int32x4*)(Bb + boff[j][1]);
        if (st) {
            gload_lds16(A8 + arow + gk, a_dst);
            gload_lds16(A8 + arow + 524288 + gk, a_dst + 8192);
        }
        __builtin_amdgcn_sched_barrier(0);   // reads issued before MFMAs
        __builtin_amdgcn_s_setprio(1);
        acc[0][0] = MFMA_I8(xa[0], xb[0], acc[0][0]);
        acc[0][1] = MFMA_I8(xa[0], xb[1], acc[0][1]);
        acc[1][0] = MFMA_I8(xa[1], xb[0], acc[1][0]);
        acc[1][1] = MFMA_I8(xa[1], xb[1], acc[1][1]);
        acc[2][0] = MFMA_I8(xa[2], xb[0], acc[2][0]);
        acc[2][1] = MFMA_I8(xa[2], xb[1], acc[2][1]);
        acc[3][0] = MFMA_I8(xa[3], xb[0], acc[3][0]);
        acc[3][1] = MFMA_I8(xa[3], xb[1], acc[3][1]);
        __builtin_amdgcn_s_setprio(0);

        // ---- half 1: refill X <- tile t+1 ks0; stage B of t+3; MFMA Y ----
        if (t < 63) {
#pragma unroll
            for (int i = 0; i < 4; i++) xa[i] = *(const int32x4*)(Abn + aoff[i][0]);
#pragma unroll
            for (int j = 0; j < 2; j++) xb[j] = *(const int32x4*)(Bbn + boff[j][0]);
        }
        if (st) {
            gload_lds16(B8T + brow + gk, b_dst);
            gload_lds16(B8T + brow + 524288 + gk, b_dst + 8192);
        }
        __builtin_amdgcn_sched_barrier(0);
        __builtin_amdgcn_s_setprio(1);
        acc[0][0] = MFMA_I8(ya[0], yb[0], acc[0][0]);
        acc[0][1] = MFMA_I8(ya[0], yb[1], acc[0][1]);
        acc[1][0] = MFMA_I8(ya[1], yb[0], acc[1][0]);
        acc[1][1] = MFMA_I8(ya[1], yb[1], acc[1][1]);
        acc[2][0] = MFMA_I8(ya[2], yb[0], acc[2][0]);
        acc[2][1] = MFMA_I8(ya[2], yb[1], acc[2][1]);
        acc[3][0] = MFMA_I8(ya[3], yb[0], acc[3][0]);
        acc[3][1] = MFMA_I8(ya[3], yb[1], acc[3][1]);
        __builtin_amdgcn_s_setprio(0);
    }

    // Epilogue. C/D: col = lane&31, row = (reg&3) + 8*(reg>>2) + 4*kh
#pragma unroll
    for (int i = 0; i < 4; i++) {
#pragma unroll
        for (int r = 0; r < 16; r++) {
            const int gm = bm + wm + i * 32 + (r & 3) + 8 * (r >> 2) + 4 * kh;
            const int rcorr = -32 * rs[gm] - 8650752;
#pragma unroll
            for (int j = 0; j < 2; j++) {
                const int gn = bn + wn + j * 32 + mr;
                const int v = acc[i][j][r] + rcorr + 66 * sy[gn];
                C[(size_t)gm * 4096 + gn] = 7.5e-4f * (float)v;
            }
        }
    }
}

// ---------------------------------------------------------------------------
extern "C" void kernel_launch(void* const* d_in, const int* in_sizes, int n_in,
                              void* d_out, int out_size, void* d_ws, size_t ws_size,
                              hipStream_t stream) {
    const float* x = (const float*)d_in[0];  // [4096,4096] int8-valued
    const float* y = (const float*)d_in[1];  // [4096,4096] uint8-valued
    float* out = (float*)d_out;

    char* ws = (char*)d_ws;
    signed char* A8  = (signed char*)ws;                         // 16 MiB
    signed char* B8T = (signed char*)(ws + (16u << 20));         // 16 MiB
    int* rs = (int*)(ws + (32u << 20));                          // 16 KiB
    int* sy = (int*)(ws + (32u << 20) + (16u << 10));            // 16 KiB

    hipMemsetAsync(sy, 0, 4096 * sizeof(int), stream);
    quant_xy<<<5120, 256, 0, stream>>>(x, y, A8, B8T, rs, sy);
    gemm_i8<<<256, 512, 0, stream>>>(A8, B8T, rs, sy, out);
}